// Round 10
// baseline (1503.326 us; speedup 1.0000x reference)
//
#include <hip/hip_runtime.h>
#include <math.h>

#define NN   262144      // nodes
#define CIN  200         // input channels
#define EE   2097152     // edges
#define NB   (2*NN)      // flat count/ptr sections: [row | col]
#define EPSV 1e-5f

typedef __bf16 bf16x8 __attribute__((ext_vector_type(8)));
typedef float  f32x4  __attribute__((ext_vector_type(4)));

__device__ __forceinline__ unsigned short f2bf(float f) {
    unsigned int u = __float_as_uint(f);
    unsigned int r = (u + 0x7fffu + ((u >> 16) & 1u)) >> 16;
    return (unsigned short)r;
}
__device__ __forceinline__ float bf2f(unsigned short u) {
    return __uint_as_float(((unsigned int)u) << 16);
}

// ---------------- stem GEMM: t = x @ W + b, fused BN stats ---------------------
__global__ __launch_bounds__(256) void stem_gemm(
    const float* __restrict__ x, const float* __restrict__ W,
    const float* __restrict__ bias, float* __restrict__ t,
    float* __restrict__ stats)
{
    __shared__ float sA[40][64];
    __shared__ float sB[40][64];
    __shared__ float cs[64], cs2[64];
    const int tid = threadIdx.x;
    const int rid = tid >> 4;
    const int cid = tid & 15;
    const int row0 = blockIdx.x * 64;

    if (tid < 64) { cs[tid] = 0.f; cs2[tid] = 0.f; }

    float acc[4][4];
#pragma unroll
    for (int i = 0; i < 4; ++i)
#pragma unroll
        for (int j = 0; j < 4; ++j) acc[i][j] = 0.f;

    for (int k0 = 0; k0 < CIN; k0 += 40) {
        __syncthreads();
        for (int idx = tid; idx < 64 * 40; idx += 256) {
            int r = idx / 40, kk = idx % 40;
            sA[kk][r] = x[(size_t)(row0 + r) * CIN + k0 + kk];
        }
        for (int idx = tid; idx < 40 * 64; idx += 256) {
            int kk = idx >> 6, c = idx & 63;
            sB[kk][c] = W[(k0 + kk) * 64 + c];
        }
        __syncthreads();
#pragma unroll
        for (int kk = 0; kk < 40; ++kk) {
            const float4 a4 = *(const float4*)&sA[kk][rid * 4];
            const float4 b4 = *(const float4*)&sB[kk][cid * 4];
            acc[0][0] = fmaf(a4.x, b4.x, acc[0][0]);
            acc[0][1] = fmaf(a4.x, b4.y, acc[0][1]);
            acc[0][2] = fmaf(a4.x, b4.z, acc[0][2]);
            acc[0][3] = fmaf(a4.x, b4.w, acc[0][3]);
            acc[1][0] = fmaf(a4.y, b4.x, acc[1][0]);
            acc[1][1] = fmaf(a4.y, b4.y, acc[1][1]);
            acc[1][2] = fmaf(a4.y, b4.z, acc[1][2]);
            acc[1][3] = fmaf(a4.y, b4.w, acc[1][3]);
            acc[2][0] = fmaf(a4.z, b4.x, acc[2][0]);
            acc[2][1] = fmaf(a4.z, b4.y, acc[2][1]);
            acc[2][2] = fmaf(a4.z, b4.z, acc[2][2]);
            acc[2][3] = fmaf(a4.z, b4.w, acc[2][3]);
            acc[3][0] = fmaf(a4.w, b4.x, acc[3][0]);
            acc[3][1] = fmaf(a4.w, b4.y, acc[3][1]);
            acc[3][2] = fmaf(a4.w, b4.z, acc[3][2]);
            acc[3][3] = fmaf(a4.w, b4.w, acc[3][3]);
        }
    }
    const float4 bb = *(const float4*)&bias[cid * 4];
    float sj[4] = {0.f, 0.f, 0.f, 0.f}, sj2[4] = {0.f, 0.f, 0.f, 0.f};
#pragma unroll
    for (int i = 0; i < 4; ++i) {
        float4 o;
        o.x = acc[i][0] + bb.x;
        o.y = acc[i][1] + bb.y;
        o.z = acc[i][2] + bb.z;
        o.w = acc[i][3] + bb.w;
        sj[0] += o.x; sj2[0] += o.x * o.x;
        sj[1] += o.y; sj2[1] += o.y * o.y;
        sj[2] += o.z; sj2[2] += o.z * o.z;
        sj[3] += o.w; sj2[3] += o.w * o.w;
        *(float4*)&t[(size_t)(row0 + rid * 4 + i) * 64 + cid * 4] = o;
    }
    __syncthreads();   // cs/cs2 init visible (also sA/sB done)
#pragma unroll
    for (int j = 0; j < 4; ++j) {
        atomicAdd(&cs[cid * 4 + j], sj[j]);
        atomicAdd(&cs2[cid * 4 + j], sj2[j]);
    }
    __syncthreads();
    if (tid < 64) {
        atomicAdd(&stats[tid],      cs[tid]);
        atomicAdd(&stats[64 + tid], cs2[tid]);
    }
}

// fold BN into per-channel affine:  bn(v) = v*a + c
__global__ void finalize_bn(const float* __restrict__ stats,
                            const float* __restrict__ g, const float* __restrict__ b,
                            float* __restrict__ ac)
{
    int c = threadIdx.x;
    float mean = stats[c] * (1.f / NN);
    float var  = stats[64 + c] * (1.f / NN) - mean * mean;
    float rstd = rsqrtf(var + EPSV);
    float a = g[c] * rstd;
    ac[c]      = a;
    ac[64 + c] = b[c] - mean * a;
}

// ---- ln: xnb = bf16(LN(leaky?(affine(u)))) ------------------------------------
template <int RELU>
__global__ __launch_bounds__(256) void ln_kernel(
    const float* __restrict__ u, const float* __restrict__ ac,
    const float* __restrict__ lng, const float* __restrict__ lnb,
    unsigned short* __restrict__ xnb)
{
    const int lane = threadIdx.x & 63;
    const int wid  = (blockIdx.x * 256 + threadIdx.x) >> 6;
    const int nw   = (gridDim.x * 256) >> 6;
    const float a  = ac[lane],  c0 = ac[64 + lane];
    const float g  = lng[lane], bl = lnb[lane];

    for (int row = wid; row < NN; row += nw) {
        float v = u[(size_t)row * 64 + lane];
        v = v * a + c0;
        if (RELU) v = (v > 0.f) ? v : 0.01f * v;
        float s = v;
#pragma unroll
        for (int off = 32; off > 0; off >>= 1) s += __shfl_xor(s, off);
        float mean = s * (1.f / 64.f);
        float d = v - mean;
        float s2 = d * d;
#pragma unroll
        for (int off = 32; off > 0; off >>= 1) s2 += __shfl_xor(s2, off);
        float rstd = rsqrtf(s2 * (1.f / 64.f) + EPSV);
        float o = d * rstd * g + bl;
        xnb[(size_t)row * 64 + lane] = f2bf(o);
    }
}

// ================= CSR build (graph identical for both layers) ==================
__global__ __launch_bounds__(256) void hist_kernel(
    const int* __restrict__ rowsrc, const int* __restrict__ colsrc,
    int* __restrict__ cnt)
{
    for (int i = blockIdx.x * 256 + threadIdx.x; i < EE; i += gridDim.x * 256) {
        atomicAdd(&cnt[rowsrc[i]], 1);
        atomicAdd(&cnt[NN + colsrc[i]], 1);
    }
}

__global__ __launch_bounds__(256) void scan1_kernel(
    const int* __restrict__ cnt, int* __restrict__ bsum)
{
    const int t = threadIdx.x;
    const int base = blockIdx.x * 1024 + t * 4;
    int s = cnt[base] + cnt[base + 1] + cnt[base + 2] + cnt[base + 3];
    __shared__ int sm[256];
    sm[t] = s;
    __syncthreads();
    for (int off = 1; off < 256; off <<= 1) {
        int v = (t >= off) ? sm[t - off] : 0;
        __syncthreads();
        sm[t] += v;
        __syncthreads();
    }
    if (t == 255) bsum[blockIdx.x] = sm[255];
}

__global__ __launch_bounds__(512) void scan2_kernel(
    const int* __restrict__ bsum, int* __restrict__ bpre, int* __restrict__ ptr)
{
    const int t = threadIdx.x;
    __shared__ int sm[512];
    int orig = bsum[t];
    sm[t] = orig;
    __syncthreads();
    for (int off = 1; off < 512; off <<= 1) {
        int v = (t >= off) ? sm[t - off] : 0;
        __syncthreads();
        sm[t] += v;
        __syncthreads();
    }
    bpre[t] = sm[t] - orig;
    if (t == 0) ptr[NB] = 2 * EE;
}

__global__ __launch_bounds__(256) void scan3_kernel(
    const int* __restrict__ cnt, const int* __restrict__ bpre,
    int* __restrict__ ptr, int* __restrict__ cursor)
{
    const int t = threadIdx.x;
    const int base = blockIdx.x * 1024 + t * 4;
    int c0 = cnt[base], c1 = cnt[base + 1], c2 = cnt[base + 2], c3 = cnt[base + 3];
    int tsum = c0 + c1 + c2 + c3;
    __shared__ int sm[256];
    sm[t] = tsum;
    __syncthreads();
    for (int off = 1; off < 256; off <<= 1) {
        int v = (t >= off) ? sm[t - off] : 0;
        __syncthreads();
        sm[t] += v;
        __syncthreads();
    }
    int p = bpre[blockIdx.x] + sm[t] - tsum;
    ptr[base] = p;     cursor[base] = p;     p += c0;
    ptr[base + 1] = p; cursor[base + 1] = p; p += c1;
    ptr[base + 2] = p; cursor[base + 2] = p; p += c2;
    ptr[base + 3] = p; cursor[base + 3] = p;
}

// ---- windowed fill: 16 windows x 32768 flat-nodes (2.1 MB CSR window each) ----
__global__ __launch_bounds__(256) void fill_win(
    const int* __restrict__ rowsrc, const int* __restrict__ rowdst,
    const float* __restrict__ ratt,
    const int* __restrict__ colsrc, const int* __restrict__ coldst,
    const float* __restrict__ catt,
    int* __restrict__ cursor, int2* __restrict__ edges)
{
    const int x   = blockIdx.x & 7;
    const int sub = blockIdx.x >> 3;
    const int tid = sub * 256 + threadIdx.x;
    const int NT  = (gridDim.x >> 3) * 256;

    {
        const int w = x;
        for (int i = tid; i < EE; i += NT) {
            int s = rowsrc[i];
            if ((s >> 15) == w) {
                int q = atomicAdd(&cursor[s], 1);
                edges[q] = make_int2(rowdst[i], __float_as_int(ratt[i]));
            }
        }
    }
    {
        const int w = x + 8;
        for (int i = tid; i < EE; i += NT) {
            int s = NN + colsrc[i];
            if ((s >> 15) == w) {
                int q = atomicAdd(&cursor[s], 1);
                edges[q] = make_int2(coldst[i], __float_as_int(catt[i]));
            }
        }
    }
}

// ---- pure gather, 4 concurrent streams per wave; NT hints to protect L2 -------
__global__ __launch_bounds__(256) void gather_kernel(
    const unsigned short* __restrict__ xnb,
    const int* __restrict__ ptr, const long long* __restrict__ edges,
    unsigned short* __restrict__ rxb, unsigned short* __restrict__ cxb,
    float2* __restrict__ attsum)
{
    const int lane = threadIdx.x & 63;
    const int wid  = (blockIdx.x * 256 + threadIdx.x) >> 6;
    const int nw   = (gridDim.x * 256) >> 6;
    const int HALF = NN / 2;

    for (int n = wid; n < HALF; n += nw) {
        const int m = n + HALF;
        const int i0 = ptr[n],      e0 = ptr[n + 1];
        const int i1 = ptr[NN + n], e1 = ptr[NN + n + 1];
        const int i2 = ptr[m],      e2 = ptr[m + 1];
        const int i3 = ptr[NN + m], e3 = ptr[NN + m + 1];
        const int len0 = e0 - i0, len1 = e1 - i1, len2 = e2 - i2, len3 = e3 - i3;
        int maxlen = max(max(len0, len1), max(len2, len3));

        float rx0 = 0.f, cx0 = 0.f, rx1 = 0.f, cx1 = 0.f;
        float ras0 = 0.f, cas0 = 0.f, ras1 = 0.f, cas1 = 0.f;

#pragma unroll 2
        for (int k = 0; k < maxlen; ++k) {
            int j0 = min(i0 + ((k < len0) ? k : 0), 2 * EE - 1);
            int j1 = min(i1 + ((k < len1) ? k : 0), 2 * EE - 1);
            int j2 = min(i2 + ((k < len2) ? k : 0), 2 * EE - 1);
            int j3 = min(i3 + ((k < len3) ? k : 0), 2 * EE - 1);
            long long q0 = __builtin_nontemporal_load(&edges[j0]);
            long long q1 = __builtin_nontemporal_load(&edges[j1]);
            long long q2 = __builtin_nontemporal_load(&edges[j2]);
            long long q3 = __builtin_nontemporal_load(&edges[j3]);
            int d0 = (int)q0, d1 = (int)q1, d2 = (int)q2, d3 = (int)q3;
            float v0 = bf2f(xnb[(size_t)d0 * 64 + lane]);
            float v1 = bf2f(xnb[(size_t)d1 * 64 + lane]);
            float v2 = bf2f(xnb[(size_t)d2 * 64 + lane]);
            float v3 = bf2f(xnb[(size_t)d3 * 64 + lane]);
            float a0 = (k < len0) ? __int_as_float((int)(q0 >> 32)) : 0.f;
            float a1 = (k < len1) ? __int_as_float((int)(q1 >> 32)) : 0.f;
            float a2 = (k < len2) ? __int_as_float((int)(q2 >> 32)) : 0.f;
            float a3 = (k < len3) ? __int_as_float((int)(q3 >> 32)) : 0.f;
            rx0 = fmaf(v0, a0, rx0); ras0 += a0;
            cx0 = fmaf(v1, a1, cx0); cas0 += a1;
            rx1 = fmaf(v2, a2, rx1); ras1 += a2;
            cx1 = fmaf(v3, a3, cx1); cas1 += a3;
        }

        __builtin_nontemporal_store(f2bf(rx0), &rxb[(size_t)n * 64 + lane]);
        __builtin_nontemporal_store(f2bf(cx0), &cxb[(size_t)n * 64 + lane]);
        __builtin_nontemporal_store(f2bf(rx1), &rxb[(size_t)m * 64 + lane]);
        __builtin_nontemporal_store(f2bf(cx1), &cxb[(size_t)m * 64 + lane]);
        if (lane == 0) {
            __builtin_nontemporal_store(ras0, &attsum[n].x);
            __builtin_nontemporal_store(cas0, &attsum[n].y);
            __builtin_nontemporal_store(ras1, &attsum[m].x);
            __builtin_nontemporal_store(cas1, &attsum[m].y);
        }
    }
}

// ---- weight pre-swizzle into MFMA B-fragment layout (bf16) --------------------
__global__ __launch_bounds__(256) void w_convert(
    const float* __restrict__ Wrv, const float* __restrict__ Wcv,
    unsigned short* __restrict__ wbuf)
{
    int idx = blockIdx.x * 256 + threadIdx.x;   // 0..16383
    int e    = idx & 7;
    int lane = (idx >> 3) & 63;
    int t    = (idx >> 9) & 3;
    int kb   = (idx >> 11) & 1;
    int m    = (idx >> 12) & 1;
    int L    = (idx >> 13) & 1;
    const float* W = (m ? Wcv : Wrv) + L * 4096;
    float w = W[(kb * 32 + ((lane >> 4) & 3) * 8 + e) * 64 + t * 16 + (lane & 15)];
    wbuf[idx] = f2bf(w);
}

// ---- MFMA epilogue: out = xnb + rx@Wr + cx@Wc + ras·br + cas·bc; fused stats --
__global__ __launch_bounds__(256) void gemv_mfma(
    const unsigned short* __restrict__ rxb, const unsigned short* __restrict__ cxb,
    const unsigned short* __restrict__ xnb, const float2* __restrict__ attsum,
    const unsigned short* __restrict__ wb16,
    const float* __restrict__ br, const float* __restrict__ bc,
    float* __restrict__ out, float* __restrict__ stats)
{
    const int lane = threadIdx.x & 63;
    const int wloc = threadIdx.x >> 6;
    const int wid  = (blockIdx.x * 256 + threadIdx.x) >> 6;
    const int nw   = (gridDim.x * 256) >> 6;
    const int lo   = lane & 15;
    const int hi   = lane >> 4;

    const bf16x8* wb = (const bf16x8*)wb16;
    bf16x8 bfr[2][2][4];
#pragma unroll
    for (int m = 0; m < 2; ++m)
#pragma unroll
        for (int kb = 0; kb < 2; ++kb)
#pragma unroll
            for (int t = 0; t < 4; ++t)
                bfr[m][kb][t] = wb[((m * 2 + kb) * 4 + t) * 64 + lane];

    float brv4[4], bcv4[4];
#pragma unroll
    for (int t = 0; t < 4; ++t) {
        brv4[t] = br[t * 16 + lo];
        bcv4[t] = bc[t * 16 + lo];
    }

    float ss[4] = {0.f, 0.f, 0.f, 0.f}, ss2[4] = {0.f, 0.f, 0.f, 0.f};
    const bf16x8* ra = (const bf16x8*)rxb;
    const bf16x8* ca = (const bf16x8*)cxb;

    for (int tile = wid; tile < NN / 16; tile += nw) {
        const int n0 = tile * 16;
        const int arow = n0 + lo;
        bf16x8 a0 = ra[arow * 8 + hi];
        bf16x8 a1 = ra[arow * 8 + 4 + hi];
        bf16x8 c0 = ca[arow * 8 + hi];
        bf16x8 c1 = ca[arow * 8 + 4 + hi];
        float2 an[4];
#pragma unroll
        for (int r = 0; r < 4; ++r) an[r] = attsum[n0 + hi * 4 + r];

#pragma unroll
        for (int t = 0; t < 4; ++t) {
            f32x4 acc = {0.f, 0.f, 0.f, 0.f};
            acc = __builtin_amdgcn_mfma_f32_16x16x32_bf16(a0, bfr[0][0][t], acc, 0, 0, 0);
            acc = __builtin_amdgcn_mfma_f32_16x16x32_bf16(a1, bfr[0][1][t], acc, 0, 0, 0);
            acc = __builtin_amdgcn_mfma_f32_16x16x32_bf16(c0, bfr[1][0][t], acc, 0, 0, 0);
            acc = __builtin_amdgcn_mfma_f32_16x16x32_bf16(c1, bfr[1][1][t], acc, 0, 0, 0);
            const int col = t * 16 + lo;
#pragma unroll
            for (int r = 0; r < 4; ++r) {
                const int n = n0 + hi * 4 + r;
                float v = acc[r] + bf2f(xnb[(size_t)n * 64 + col])
                        + an[r].x * brv4[t] + an[r].y * bcv4[t];
                out[(size_t)n * 64 + col] = v;
                ss[t] += v;
                ss2[t] += v * v;
            }
        }
    }

    // stats reduce: lanes sharing the same (lane&15) hold the same channels
#pragma unroll
    for (int t = 0; t < 4; ++t) {
        ss[t]  += __shfl_xor(ss[t], 16);  ss[t]  += __shfl_xor(ss[t], 32);
        ss2[t] += __shfl_xor(ss2[t], 16); ss2[t] += __shfl_xor(ss2[t], 32);
    }
    __shared__ float ls[4][64], ls2[4][64];
    if (lo == lane) {   // lanes 0..15
#pragma unroll
        for (int t = 0; t < 4; ++t) {
            ls[wloc][t * 16 + lane]  = ss[t];
            ls2[wloc][t * 16 + lane] = ss2[t];
        }
    }
    __syncthreads();
    if (threadIdx.x < 64) {
        int ch = threadIdx.x;
        atomicAdd(&stats[ch],      ls[0][ch] + ls[1][ch] + ls[2][ch] + ls[3][ch]);
        atomicAdd(&stats[64 + ch], ls2[0][ch] + ls2[1][ch] + ls2[2][ch] + ls2[3][ch]);
    }
}

// ------ fused output: affine+leaky -> logits = h@smW + b -> softmax ------------
__global__ __launch_bounds__(256) void out_kernel(
    const float* __restrict__ agg, const float* __restrict__ ac,
    const float* __restrict__ smW, const float* __restrict__ smb,
    float* __restrict__ out)
{
    __shared__ float sW[64 * 16];
    for (int i = threadIdx.x; i < 64 * 16; i += 256) sW[i] = smW[i];
    __syncthreads();
    const int j = threadIdx.x & 15;
    const int rloc = threadIdx.x >> 4;
    const float bj = smb[j];
    for (int row = blockIdx.x * 16 + rloc; row < NN; row += gridDim.x * 16) {
        float acc = bj;
#pragma unroll
        for (int k = 0; k < 64; ++k) {
            float v = agg[(size_t)row * 64 + k];
            v = v * ac[k] + ac[64 + k];
            v = (v > 0.f) ? v : 0.01f * v;
            acc = fmaf(v, sW[k * 16 + j], acc);
        }
        float m = acc;
#pragma unroll
        for (int off = 8; off > 0; off >>= 1) m = fmaxf(m, __shfl_xor(m, off));
        float e = expf(acc - m);
        float ssum = e;
#pragma unroll
        for (int off = 8; off > 0; off >>= 1) ssum += __shfl_xor(ssum, off);
        out[(size_t)row * 16 + j] = e / ssum;
    }
}

// ------------------------------------------------------------------------------
extern "C" void kernel_launch(void* const* d_in, const int* in_sizes, int n_in,
                              void* d_out, int out_size, void* d_ws, size_t ws_size,
                              hipStream_t stream)
{
    const float* x        = (const float*)d_in[0];
    const float* row_att  = (const float*)d_in[1];
    const float* col_att  = (const float*)d_in[2];
    const float* prelin_W = (const float*)d_in[3];
    const float* prelin_b = (const float*)d_in[4];
    const float* bn0_g    = (const float*)d_in[5];
    const float* bn0_b    = (const float*)d_in[6];
    const float* ln_g     = (const float*)d_in[7];
    const float* ln_b     = (const float*)d_in[8];
    const float* Wrv      = (const float*)d_in[9];
    const float* brv      = (const float*)d_in[10];
    const float* Wcv      = (const float*)d_in[11];
    const float* bcv      = (const float*)d_in[12];
    const float* bn_g     = (const float*)d_in[13];
    const float* bn_b     = (const float*)d_in[14];
    const float* sm_W     = (const float*)d_in[15];
    const float* sm_b     = (const float*)d_in[16];
    const int*   rowsrc   = (const int*)d_in[17];
    const int*   rowdst   = (const int*)d_in[18];
    const int*   colsrc   = (const int*)d_in[19];
    const int*   coldst   = (const int*)d_in[20];
    float* out = (float*)d_out;

    // ---- workspace layout (~180 MB) ----
    const size_t NH = (size_t)NN * 64;
    float* A  = (float*)d_ws;                    // stem out / layer out (fp32)

    char* extra = (char*)(A + NH);
    unsigned short* xnb = (unsigned short*)extra; extra += NH * sizeof(short);
    unsigned short* rxb = (unsigned short*)extra; extra += NH * sizeof(short);
    unsigned short* cxb = (unsigned short*)extra; extra += NH * sizeof(short);
    float2* attsum = (float2*)extra;              extra += (size_t)NN * sizeof(float2);
    float* stats  = (float*)extra;                extra += 3 * 128 * sizeof(float);
    float* ac     = (float*)extra;                extra += 3 * 128 * sizeof(float);
    unsigned short* wbuf = (unsigned short*)extra; extra += 16384 * sizeof(short);
    int*   bsum   = (int*)extra;                  extra += 512 * sizeof(int);
    int*   bpre   = (int*)extra;                  extra += 512 * sizeof(int);
    int*   ptr    = (int*)extra;                  extra += (NB + 1) * sizeof(int);
    int*   counts = (int*)extra;                  extra += NB * sizeof(int);
    int*   cursor = (int*)extra;                  extra += NB * sizeof(int);
    int2*  edges  = (int2*)extra;                 extra += 2 * (size_t)EE * sizeof(int2);

    hipMemsetAsync(stats, 0, 3 * 128 * sizeof(float), stream);
    hipMemsetAsync(counts, 0, NB * sizeof(int), stream);

    // ---- CSR build (used by both layers) ----
    hist_kernel<<<2048, 256, 0, stream>>>(rowsrc, colsrc, counts);
    scan1_kernel<<<512, 256, 0, stream>>>(counts, bsum);
    scan2_kernel<<<1, 512, 0, stream>>>(bsum, bpre, ptr);
    scan3_kernel<<<512, 256, 0, stream>>>(counts, bpre, ptr, cursor);
    fill_win<<<2048, 256, 0, stream>>>(rowsrc, rowdst, row_att,
                                       colsrc, coldst, col_att,
                                       cursor, edges);
    w_convert<<<64, 256, 0, stream>>>(Wrv, Wcv, wbuf);

    // ---- stem (stats fused) ----
    stem_gemm<<<NN / 64, 256, 0, stream>>>(x, prelin_W, prelin_b, A, stats);
    finalize_bn<<<1, 64, 0, stream>>>(stats, bn0_g, bn0_b, ac);

    // ---- layer 0 ----
    ln_kernel<0><<<4096, 256, 0, stream>>>(A, ac, ln_g, ln_b, xnb);
    gather_kernel<<<8192, 256, 0, stream>>>(xnb, ptr, (const long long*)edges,
                                            rxb, cxb, attsum);
    gemv_mfma<<<2048, 256, 0, stream>>>(rxb, cxb, xnb, attsum, wbuf,
                                        brv, bcv, A, stats + 128);
    finalize_bn<<<1, 64, 0, stream>>>(stats + 128, bn_g, bn_b, ac + 128);

    // ---- layer 1 ----
    ln_kernel<1><<<4096, 256, 0, stream>>>(A, ac + 128, ln_g + 64, ln_b + 64, xnb);
    gather_kernel<<<8192, 256, 0, stream>>>(xnb, ptr, (const long long*)edges,
                                            rxb, cxb, attsum);
    gemv_mfma<<<2048, 256, 0, stream>>>(rxb, cxb, xnb, attsum, wbuf + 8192,
                                        brv + 64, bcv + 64, A, stats + 256);
    finalize_bn<<<1, 64, 0, stream>>>(stats + 256, bn_g + 64, bn_b + 64, ac + 256);

    // ---- output head ----
    out_kernel<<<2048, 256, 0, stream>>>(A, ac + 256, sm_W, sm_b, out);
}

// Round 11
// 1375.014 us; speedup vs baseline: 1.0933x; 1.0933x over previous
//
#include <hip/hip_runtime.h>
#include <math.h>

#define NN   262144      // nodes
#define CIN  200         // input channels
#define EE   2097152     // edges
#define NB   (2*NN)      // flat count/ptr sections: [row | col]
#define EPSV 1e-5f

typedef __bf16 bf16x8 __attribute__((ext_vector_type(8)));
typedef float  f32x4  __attribute__((ext_vector_type(4)));

__device__ __forceinline__ unsigned short f2bf(float f) {
    unsigned int u = __float_as_uint(f);
    unsigned int r = (u + 0x7fffu + ((u >> 16) & 1u)) >> 16;
    return (unsigned short)r;
}
__device__ __forceinline__ float bf2f(unsigned short u) {
    return __uint_as_float(((unsigned int)u) << 16);
}

// ------- stem GEMM: t = bf16(x @ W + b), fused fp32 BN stats -------------------
__global__ __launch_bounds__(256) void stem_gemm(
    const float* __restrict__ x, const float* __restrict__ W,
    const float* __restrict__ bias, unsigned short* __restrict__ t,
    float* __restrict__ stats)
{
    __shared__ float sA[40][64];
    __shared__ float sB[40][64];
    __shared__ float cs[64], cs2[64];
    const int tid = threadIdx.x;
    const int rid = tid >> 4;
    const int cid = tid & 15;
    const int row0 = blockIdx.x * 64;

    if (tid < 64) { cs[tid] = 0.f; cs2[tid] = 0.f; }

    float acc[4][4];
#pragma unroll
    for (int i = 0; i < 4; ++i)
#pragma unroll
        for (int j = 0; j < 4; ++j) acc[i][j] = 0.f;

    for (int k0 = 0; k0 < CIN; k0 += 40) {
        __syncthreads();
        for (int idx = tid; idx < 64 * 40; idx += 256) {
            int r = idx / 40, kk = idx % 40;
            sA[kk][r] = x[(size_t)(row0 + r) * CIN + k0 + kk];
        }
        for (int idx = tid; idx < 40 * 64; idx += 256) {
            int kk = idx >> 6, c = idx & 63;
            sB[kk][c] = W[(k0 + kk) * 64 + c];
        }
        __syncthreads();
#pragma unroll
        for (int kk = 0; kk < 40; ++kk) {
            const float4 a4 = *(const float4*)&sA[kk][rid * 4];
            const float4 b4 = *(const float4*)&sB[kk][cid * 4];
            acc[0][0] = fmaf(a4.x, b4.x, acc[0][0]);
            acc[0][1] = fmaf(a4.x, b4.y, acc[0][1]);
            acc[0][2] = fmaf(a4.x, b4.z, acc[0][2]);
            acc[0][3] = fmaf(a4.x, b4.w, acc[0][3]);
            acc[1][0] = fmaf(a4.y, b4.x, acc[1][0]);
            acc[1][1] = fmaf(a4.y, b4.y, acc[1][1]);
            acc[1][2] = fmaf(a4.y, b4.z, acc[1][2]);
            acc[1][3] = fmaf(a4.y, b4.w, acc[1][3]);
            acc[2][0] = fmaf(a4.z, b4.x, acc[2][0]);
            acc[2][1] = fmaf(a4.z, b4.y, acc[2][1]);
            acc[2][2] = fmaf(a4.z, b4.z, acc[2][2]);
            acc[2][3] = fmaf(a4.z, b4.w, acc[2][3]);
            acc[3][0] = fmaf(a4.w, b4.x, acc[3][0]);
            acc[3][1] = fmaf(a4.w, b4.y, acc[3][1]);
            acc[3][2] = fmaf(a4.w, b4.z, acc[3][2]);
            acc[3][3] = fmaf(a4.w, b4.w, acc[3][3]);
        }
    }
    const float4 bb = *(const float4*)&bias[cid * 4];
    float sj[4] = {0.f, 0.f, 0.f, 0.f}, sj2[4] = {0.f, 0.f, 0.f, 0.f};
#pragma unroll
    for (int i = 0; i < 4; ++i) {
        float o0 = acc[i][0] + bb.x;
        float o1 = acc[i][1] + bb.y;
        float o2 = acc[i][2] + bb.z;
        float o3 = acc[i][3] + bb.w;
        sj[0] += o0; sj2[0] += o0 * o0;
        sj[1] += o1; sj2[1] += o1 * o1;
        sj[2] += o2; sj2[2] += o2 * o2;
        sj[3] += o3; sj2[3] += o3 * o3;
        ushort4 st;
        st.x = f2bf(o0); st.y = f2bf(o1); st.z = f2bf(o2); st.w = f2bf(o3);
        *(ushort4*)&t[(size_t)(row0 + rid * 4 + i) * 64 + cid * 4] = st;
    }
    __syncthreads();
#pragma unroll
    for (int j = 0; j < 4; ++j) {
        atomicAdd(&cs[cid * 4 + j], sj[j]);
        atomicAdd(&cs2[cid * 4 + j], sj2[j]);
    }
    __syncthreads();
    if (tid < 64) {
        atomicAdd(&stats[tid],      cs[tid]);
        atomicAdd(&stats[64 + tid], cs2[tid]);
    }
}

// fold BN into per-channel affine:  bn(v) = v*a + c
__global__ void finalize_bn(const float* __restrict__ stats,
                            const float* __restrict__ g, const float* __restrict__ b,
                            float* __restrict__ ac)
{
    int c = threadIdx.x;
    float mean = stats[c] * (1.f / NN);
    float var  = stats[64 + c] * (1.f / NN) - mean * mean;
    float rstd = rsqrtf(var + EPSV);
    float a = g[c] * rstd;
    ac[c]      = a;
    ac[64 + c] = b[c] - mean * a;
}

// ---- ln: xnb = bf16(LN(leaky?(affine(u_bf16)))) -------------------------------
template <int RELU>
__global__ __launch_bounds__(256) void ln_kernel(
    const unsigned short* __restrict__ u, const float* __restrict__ ac,
    const float* __restrict__ lng, const float* __restrict__ lnb,
    unsigned short* __restrict__ xnb)
{
    const int lane = threadIdx.x & 63;
    const int wid  = (blockIdx.x * 256 + threadIdx.x) >> 6;
    const int nw   = (gridDim.x * 256) >> 6;
    const float a  = ac[lane],  c0 = ac[64 + lane];
    const float g  = lng[lane], bl = lnb[lane];

    for (int row = wid; row < NN; row += nw) {
        float v = bf2f(u[(size_t)row * 64 + lane]);
        v = v * a + c0;
        if (RELU) v = (v > 0.f) ? v : 0.01f * v;
        float s = v;
#pragma unroll
        for (int off = 32; off > 0; off >>= 1) s += __shfl_xor(s, off);
        float mean = s * (1.f / 64.f);
        float d = v - mean;
        float s2 = d * d;
#pragma unroll
        for (int off = 32; off > 0; off >>= 1) s2 += __shfl_xor(s2, off);
        float rstd = rsqrtf(s2 * (1.f / 64.f) + EPSV);
        float o = d * rstd * g + bl;
        xnb[(size_t)row * 64 + lane] = f2bf(o);
    }
}

// ================= CSR build (graph identical for both layers) ==================
__global__ __launch_bounds__(256) void hist_kernel(
    const int* __restrict__ rowsrc, const int* __restrict__ colsrc,
    int* __restrict__ cnt)
{
    for (int i = blockIdx.x * 256 + threadIdx.x; i < EE; i += gridDim.x * 256) {
        atomicAdd(&cnt[rowsrc[i]], 1);
        atomicAdd(&cnt[NN + colsrc[i]], 1);
    }
}

__global__ __launch_bounds__(256) void scan1_kernel(
    const int* __restrict__ cnt, int* __restrict__ bsum)
{
    const int t = threadIdx.x;
    const int base = blockIdx.x * 1024 + t * 4;
    int s = cnt[base] + cnt[base + 1] + cnt[base + 2] + cnt[base + 3];
    __shared__ int sm[256];
    sm[t] = s;
    __syncthreads();
    for (int off = 1; off < 256; off <<= 1) {
        int v = (t >= off) ? sm[t - off] : 0;
        __syncthreads();
        sm[t] += v;
        __syncthreads();
    }
    if (t == 255) bsum[blockIdx.x] = sm[255];
}

__global__ __launch_bounds__(512) void scan2_kernel(
    const int* __restrict__ bsum, int* __restrict__ bpre, int* __restrict__ ptr)
{
    const int t = threadIdx.x;
    __shared__ int sm[512];
    int orig = bsum[t];
    sm[t] = orig;
    __syncthreads();
    for (int off = 1; off < 512; off <<= 1) {
        int v = (t >= off) ? sm[t - off] : 0;
        __syncthreads();
        sm[t] += v;
        __syncthreads();
    }
    bpre[t] = sm[t] - orig;
    if (t == 0) ptr[NB] = 2 * EE;
}

__global__ __launch_bounds__(256) void scan3_kernel(
    const int* __restrict__ cnt, const int* __restrict__ bpre,
    int* __restrict__ ptr, int* __restrict__ cursor)
{
    const int t = threadIdx.x;
    const int base = blockIdx.x * 1024 + t * 4;
    int c0 = cnt[base], c1 = cnt[base + 1], c2 = cnt[base + 2], c3 = cnt[base + 3];
    int tsum = c0 + c1 + c2 + c3;
    __shared__ int sm[256];
    sm[t] = tsum;
    __syncthreads();
    for (int off = 1; off < 256; off <<= 1) {
        int v = (t >= off) ? sm[t - off] : 0;
        __syncthreads();
        sm[t] += v;
        __syncthreads();
    }
    int p = bpre[blockIdx.x] + sm[t] - tsum;
    ptr[base] = p;     cursor[base] = p;     p += c0;
    ptr[base + 1] = p; cursor[base + 1] = p; p += c1;
    ptr[base + 2] = p; cursor[base + 2] = p; p += c2;
    ptr[base + 3] = p; cursor[base + 3] = p;
}

// ---- windowed fill: 16 windows x 32768 flat-nodes (2.1 MB CSR window each) ----
__global__ __launch_bounds__(256) void fill_win(
    const int* __restrict__ rowsrc, const int* __restrict__ rowdst,
    const float* __restrict__ ratt,
    const int* __restrict__ colsrc, const int* __restrict__ coldst,
    const float* __restrict__ catt,
    int* __restrict__ cursor, int2* __restrict__ edges)
{
    const int x   = blockIdx.x & 7;
    const int sub = blockIdx.x >> 3;
    const int tid = sub * 256 + threadIdx.x;
    const int NT  = (gridDim.x >> 3) * 256;

    {
        const int w = x;
        for (int i = tid; i < EE; i += NT) {
            int s = rowsrc[i];
            if ((s >> 15) == w) {
                int q = atomicAdd(&cursor[s], 1);
                edges[q] = make_int2(rowdst[i], __float_as_int(ratt[i]));
            }
        }
    }
    {
        const int w = x + 8;
        for (int i = tid; i < EE; i += NT) {
            int s = NN + colsrc[i];
            if ((s >> 15) == w) {
                int q = atomicAdd(&cursor[s], 1);
                edges[q] = make_int2(coldst[i], __float_as_int(catt[i]));
            }
        }
    }
}

// ---- pure gather, 4 concurrent streams per wave (R9-proven version) -----------
__global__ __launch_bounds__(256) void gather_kernel(
    const unsigned short* __restrict__ xnb,
    const int* __restrict__ ptr, const int2* __restrict__ edges,
    unsigned short* __restrict__ rxb, unsigned short* __restrict__ cxb,
    float2* __restrict__ attsum)
{
    const int lane = threadIdx.x & 63;
    const int wid  = (blockIdx.x * 256 + threadIdx.x) >> 6;
    const int nw   = (gridDim.x * 256) >> 6;
    const int HALF = NN / 2;

    for (int n = wid; n < HALF; n += nw) {
        const int m = n + HALF;
        const int i0 = ptr[n],      e0 = ptr[n + 1];
        const int i1 = ptr[NN + n], e1 = ptr[NN + n + 1];
        const int i2 = ptr[m],      e2 = ptr[m + 1];
        const int i3 = ptr[NN + m], e3 = ptr[NN + m + 1];
        const int len0 = e0 - i0, len1 = e1 - i1, len2 = e2 - i2, len3 = e3 - i3;
        int maxlen = max(max(len0, len1), max(len2, len3));

        float rx0 = 0.f, cx0 = 0.f, rx1 = 0.f, cx1 = 0.f;
        float ras0 = 0.f, cas0 = 0.f, ras1 = 0.f, cas1 = 0.f;

#pragma unroll 2
        for (int k = 0; k < maxlen; ++k) {
            int j0 = min(i0 + ((k < len0) ? k : 0), 2 * EE - 1);
            int j1 = min(i1 + ((k < len1) ? k : 0), 2 * EE - 1);
            int j2 = min(i2 + ((k < len2) ? k : 0), 2 * EE - 1);
            int j3 = min(i3 + ((k < len3) ? k : 0), 2 * EE - 1);
            int2 p0 = edges[j0];
            int2 p1 = edges[j1];
            int2 p2 = edges[j2];
            int2 p3 = edges[j3];
            float v0 = bf2f(xnb[(size_t)p0.x * 64 + lane]);
            float v1 = bf2f(xnb[(size_t)p1.x * 64 + lane]);
            float v2 = bf2f(xnb[(size_t)p2.x * 64 + lane]);
            float v3 = bf2f(xnb[(size_t)p3.x * 64 + lane]);
            float a0 = (k < len0) ? __int_as_float(p0.y) : 0.f;
            float a1 = (k < len1) ? __int_as_float(p1.y) : 0.f;
            float a2 = (k < len2) ? __int_as_float(p2.y) : 0.f;
            float a3 = (k < len3) ? __int_as_float(p3.y) : 0.f;
            rx0 = fmaf(v0, a0, rx0); ras0 += a0;
            cx0 = fmaf(v1, a1, cx0); cas0 += a1;
            rx1 = fmaf(v2, a2, rx1); ras1 += a2;
            cx1 = fmaf(v3, a3, cx1); cas1 += a3;
        }

        rxb[(size_t)n * 64 + lane] = f2bf(rx0);
        cxb[(size_t)n * 64 + lane] = f2bf(cx0);
        rxb[(size_t)m * 64 + lane] = f2bf(rx1);
        cxb[(size_t)m * 64 + lane] = f2bf(cx1);
        if (lane == 0) {
            attsum[n] = make_float2(ras0, cas0);
            attsum[m] = make_float2(ras1, cas1);
        }
    }
}

// ---- weight pre-swizzle into MFMA B-fragment layout (bf16) --------------------
__global__ __launch_bounds__(256) void w_convert(
    const float* __restrict__ Wrv, const float* __restrict__ Wcv,
    unsigned short* __restrict__ wbuf)
{
    int idx = blockIdx.x * 256 + threadIdx.x;   // 0..16383
    int e    = idx & 7;
    int lane = (idx >> 3) & 63;
    int t    = (idx >> 9) & 3;
    int kb   = (idx >> 11) & 1;
    int m    = (idx >> 12) & 1;
    int L    = (idx >> 13) & 1;
    const float* W = (m ? Wcv : Wrv) + L * 4096;
    float w = W[(kb * 32 + ((lane >> 4) & 3) * 8 + e) * 64 + t * 16 + (lane & 15)];
    wbuf[idx] = f2bf(w);
}

// ---- MFMA epilogue: out = bf16(xnb + rx@Wr + cx@Wc + ras·br + cas·bc) ---------
__global__ __launch_bounds__(256) void gemv_mfma(
    const unsigned short* __restrict__ rxb, const unsigned short* __restrict__ cxb,
    const unsigned short* __restrict__ xnb, const float2* __restrict__ attsum,
    const unsigned short* __restrict__ wb16,
    const float* __restrict__ br, const float* __restrict__ bc,
    unsigned short* __restrict__ out, float* __restrict__ stats)
{
    const int lane = threadIdx.x & 63;
    const int wloc = threadIdx.x >> 6;
    const int wid  = (blockIdx.x * 256 + threadIdx.x) >> 6;
    const int nw   = (gridDim.x * 256) >> 6;
    const int lo   = lane & 15;
    const int hi   = lane >> 4;

    const bf16x8* wb = (const bf16x8*)wb16;
    bf16x8 bfr[2][2][4];
#pragma unroll
    for (int m = 0; m < 2; ++m)
#pragma unroll
        for (int kb = 0; kb < 2; ++kb)
#pragma unroll
            for (int t = 0; t < 4; ++t)
                bfr[m][kb][t] = wb[((m * 2 + kb) * 4 + t) * 64 + lane];

    float brv4[4], bcv4[4];
#pragma unroll
    for (int t = 0; t < 4; ++t) {
        brv4[t] = br[t * 16 + lo];
        bcv4[t] = bc[t * 16 + lo];
    }

    float ss[4] = {0.f, 0.f, 0.f, 0.f}, ss2[4] = {0.f, 0.f, 0.f, 0.f};
    const bf16x8* ra = (const bf16x8*)rxb;
    const bf16x8* ca = (const bf16x8*)cxb;

    for (int tile = wid; tile < NN / 16; tile += nw) {
        const int n0 = tile * 16;
        const int arow = n0 + lo;
        bf16x8 a0 = ra[arow * 8 + hi];
        bf16x8 a1 = ra[arow * 8 + 4 + hi];
        bf16x8 c0 = ca[arow * 8 + hi];
        bf16x8 c1 = ca[arow * 8 + 4 + hi];
        float2 an[4];
#pragma unroll
        for (int r = 0; r < 4; ++r) an[r] = attsum[n0 + hi * 4 + r];

#pragma unroll
        for (int t = 0; t < 4; ++t) {
            f32x4 acc = {0.f, 0.f, 0.f, 0.f};
            acc = __builtin_amdgcn_mfma_f32_16x16x32_bf16(a0, bfr[0][0][t], acc, 0, 0, 0);
            acc = __builtin_amdgcn_mfma_f32_16x16x32_bf16(a1, bfr[0][1][t], acc, 0, 0, 0);
            acc = __builtin_amdgcn_mfma_f32_16x16x32_bf16(c0, bfr[1][0][t], acc, 0, 0, 0);
            acc = __builtin_amdgcn_mfma_f32_16x16x32_bf16(c1, bfr[1][1][t], acc, 0, 0, 0);
            const int col = t * 16 + lo;
#pragma unroll
            for (int r = 0; r < 4; ++r) {
                const int n = n0 + hi * 4 + r;
                float v = acc[r] + bf2f(xnb[(size_t)n * 64 + col])
                        + an[r].x * brv4[t] + an[r].y * bcv4[t];
                out[(size_t)n * 64 + col] = f2bf(v);
                ss[t] += v;
                ss2[t] += v * v;
            }
        }
    }

    // stats reduce: lanes sharing the same (lane&15) hold the same channels
#pragma unroll
    for (int t = 0; t < 4; ++t) {
        ss[t]  += __shfl_xor(ss[t], 16);  ss[t]  += __shfl_xor(ss[t], 32);
        ss2[t] += __shfl_xor(ss2[t], 16); ss2[t] += __shfl_xor(ss2[t], 32);
    }
    __shared__ float ls[4][64], ls2[4][64];
    if (lo == lane) {   // lanes 0..15
#pragma unroll
        for (int t = 0; t < 4; ++t) {
            ls[wloc][t * 16 + lane]  = ss[t];
            ls2[wloc][t * 16 + lane] = ss2[t];
        }
    }
    __syncthreads();
    if (threadIdx.x < 64) {
        int ch = threadIdx.x;
        atomicAdd(&stats[ch],      ls[0][ch] + ls[1][ch] + ls[2][ch] + ls[3][ch]);
        atomicAdd(&stats[64 + ch], ls2[0][ch] + ls2[1][ch] + ls2[2][ch] + ls2[3][ch]);
    }
}

// ------ fused output: affine+leaky -> logits = h@smW + b -> softmax ------------
__global__ __launch_bounds__(256) void out_kernel(
    const unsigned short* __restrict__ agg, const float* __restrict__ ac,
    const float* __restrict__ smW, const float* __restrict__ smb,
    float* __restrict__ out)
{
    __shared__ float sW[64 * 16];
    for (int i = threadIdx.x; i < 64 * 16; i += 256) sW[i] = smW[i];
    __syncthreads();
    const int j = threadIdx.x & 15;
    const int rloc = threadIdx.x >> 4;
    const float bj = smb[j];
    for (int row = blockIdx.x * 16 + rloc; row < NN; row += gridDim.x * 16) {
        float acc = bj;
#pragma unroll
        for (int k = 0; k < 64; ++k) {
            float v = bf2f(agg[(size_t)row * 64 + k]);
            v = v * ac[k] + ac[64 + k];
            v = (v > 0.f) ? v : 0.01f * v;
            acc = fmaf(v, sW[k * 16 + j], acc);
        }
        float m = acc;
#pragma unroll
        for (int off = 8; off > 0; off >>= 1) m = fmaxf(m, __shfl_xor(m, off));
        float e = expf(acc - m);
        float ssum = e;
#pragma unroll
        for (int off = 8; off > 0; off >>= 1) ssum += __shfl_xor(ssum, off);
        out[(size_t)row * 16 + j] = e / ssum;
    }
}

// ------------------------------------------------------------------------------
extern "C" void kernel_launch(void* const* d_in, const int* in_sizes, int n_in,
                              void* d_out, int out_size, void* d_ws, size_t ws_size,
                              hipStream_t stream)
{
    const float* x        = (const float*)d_in[0];
    const float* row_att  = (const float*)d_in[1];
    const float* col_att  = (const float*)d_in[2];
    const float* prelin_W = (const float*)d_in[3];
    const float* prelin_b = (const float*)d_in[4];
    const float* bn0_g    = (const float*)d_in[5];
    const float* bn0_b    = (const float*)d_in[6];
    const float* ln_g     = (const float*)d_in[7];
    const float* ln_b     = (const float*)d_in[8];
    const float* Wrv      = (const float*)d_in[9];
    const float* brv      = (const float*)d_in[10];
    const float* Wcv      = (const float*)d_in[11];
    const float* bcv      = (const float*)d_in[12];
    const float* bn_g     = (const float*)d_in[13];
    const float* bn_b     = (const float*)d_in[14];
    const float* sm_W     = (const float*)d_in[15];
    const float* sm_b     = (const float*)d_in[16];
    const int*   rowsrc   = (const int*)d_in[17];
    const int*   rowdst   = (const int*)d_in[18];
    const int*   colsrc   = (const int*)d_in[19];
    const int*   coldst   = (const int*)d_in[20];
    float* out = (float*)d_out;

    // ---- workspace layout (~150 MB) ----
    const size_t NH = (size_t)NN * 64;
    char* extra = (char*)d_ws;
    unsigned short* A   = (unsigned short*)extra; extra += NH * sizeof(short);  // layer act (bf16)
    unsigned short* xnb = (unsigned short*)extra; extra += NH * sizeof(short);
    unsigned short* rxb = (unsigned short*)extra; extra += NH * sizeof(short);
    unsigned short* cxb = (unsigned short*)extra; extra += NH * sizeof(short);
    float2* attsum = (float2*)extra;              extra += (size_t)NN * sizeof(float2);
    float* stats  = (float*)extra;                extra += 3 * 128 * sizeof(float);
    float* ac     = (float*)extra;                extra += 3 * 128 * sizeof(float);
    unsigned short* wbuf = (unsigned short*)extra; extra += 16384 * sizeof(short);
    int*   bsum   = (int*)extra;                  extra += 512 * sizeof(int);
    int*   bpre   = (int*)extra;                  extra += 512 * sizeof(int);
    int*   ptr    = (int*)extra;                  extra += (NB + 1) * sizeof(int);
    int*   counts = (int*)extra;                  extra += NB * sizeof(int);
    int*   cursor = (int*)extra;                  extra += NB * sizeof(int);
    int2*  edges  = (int2*)extra;                 extra += 2 * (size_t)EE * sizeof(int2);

    hipMemsetAsync(stats, 0, 3 * 128 * sizeof(float), stream);
    hipMemsetAsync(counts, 0, NB * sizeof(int), stream);

    // ---- CSR build (used by both layers) ----
    hist_kernel<<<2048, 256, 0, stream>>>(rowsrc, colsrc, counts);
    scan1_kernel<<<512, 256, 0, stream>>>(counts, bsum);
    scan2_kernel<<<1, 512, 0, stream>>>(bsum, bpre, ptr);
    scan3_kernel<<<512, 256, 0, stream>>>(counts, bpre, ptr, cursor);
    fill_win<<<2048, 256, 0, stream>>>(rowsrc, rowdst, row_att,
                                       colsrc, coldst, col_att,
                                       cursor, edges);
    w_convert<<<64, 256, 0, stream>>>(Wrv, Wcv, wbuf);

    // ---- stem (stats fused) ----
    stem_gemm<<<NN / 64, 256, 0, stream>>>(x, prelin_W, prelin_b, A, stats);
    finalize_bn<<<1, 64, 0, stream>>>(stats, bn0_g, bn0_b, ac);

    // ---- layer 0 ----
    ln_kernel<0><<<4096, 256, 0, stream>>>(A, ac, ln_g, ln_b, xnb);
    gather_kernel<<<8192, 256, 0, stream>>>(xnb, ptr, edges, rxb, cxb, attsum);
    gemv_mfma<<<2048, 256, 0, stream>>>(rxb, cxb, xnb, attsum, wbuf,
                                        brv, bcv, A, stats + 128);
    finalize_bn<<<1, 64, 0, stream>>>(stats + 128, bn_g, bn_b, ac + 128);

    // ---- layer 1 ----
    ln_kernel<1><<<4096, 256, 0, stream>>>(A, ac + 128, ln_g + 64, ln_b + 64, xnb);
    gather_kernel<<<8192, 256, 0, stream>>>(xnb, ptr, edges, rxb, cxb, attsum);
    gemv_mfma<<<2048, 256, 0, stream>>>(rxb, cxb, xnb, attsum, wbuf + 8192,
                                        brv + 64, bcv + 64, A, stats + 256);
    finalize_bn<<<1, 64, 0, stream>>>(stats + 256, bn_g + 64, bn_b + 64, ac + 256);

    // ---- output head ----
    out_kernel<<<2048, 256, 0, stream>>>(A, ac + 256, sm_W, sm_b, out);
}

// Round 12
// 1277.230 us; speedup vs baseline: 1.1770x; 1.0766x over previous
//
#include <hip/hip_runtime.h>
#include <math.h>

#define NN   262144      // nodes
#define CIN  200         // input channels
#define EE   2097152     // edges
#define NB   (2*NN)      // flat count/ptr sections: [row | col]
#define EPSV 1e-5f

typedef __bf16 bf16x8 __attribute__((ext_vector_type(8)));
typedef float  f32x4  __attribute__((ext_vector_type(4)));

__device__ __forceinline__ unsigned short f2bf(float f) {
    unsigned int u = __float_as_uint(f);
    unsigned int r = (u + 0x7fffu + ((u >> 16) & 1u)) >> 16;
    return (unsigned short)r;
}
__device__ __forceinline__ float bf2f(unsigned short u) {
    return __uint_as_float(((unsigned int)u) << 16);
}

// ---- stem weight pre-swizzle: W[200][64] fp32 -> B-frag bf16, K padded to 224 --
// wbufS[((kb*4+t)*64+lane)*8+e] = bf16(W[k][t*16+(lane&15)]), k=kb*32+(lane>>4)*8+e
__global__ __launch_bounds__(256) void w_convert_stem(
    const float* __restrict__ W, unsigned short* __restrict__ wbufS)
{
    int idx = blockIdx.x * 256 + threadIdx.x;    // 0..14335
    if (idx >= 28 * 64 * 8) return;
    int e    = idx & 7;
    int lane = (idx >> 3) & 63;
    int f    = idx >> 9;          // 0..27
    int t    = f & 3;
    int kb   = f >> 2;
    int k    = kb * 32 + ((lane >> 4) & 3) * 8 + e;
    float w  = (k < CIN) ? W[k * 64 + t * 16 + (lane & 15)] : 0.f;
    wbufS[idx] = f2bf(w);
}

// ------- stem via MFMA: t = bf16(x @ W + b), fused fp32 BN stats ---------------
__global__ __launch_bounds__(256) void stem_mfma(
    const float* __restrict__ x, const unsigned short* __restrict__ wbS,
    const float* __restrict__ bias, unsigned short* __restrict__ t,
    float* __restrict__ stats)
{
    const int lane = threadIdx.x & 63;
    const int wloc = threadIdx.x >> 6;
    const int lo   = lane & 15;
    const int hi   = lane >> 4;
    const int n0   = blockIdx.x * 64 + wloc * 16;   // this wave's 16 rows

    float bb4[4];
#pragma unroll
    for (int tt = 0; tt < 4; ++tt) bb4[tt] = bias[tt * 16 + lo];

    f32x4 acc[4];
#pragma unroll
    for (int tt = 0; tt < 4; ++tt) acc[tt] = (f32x4){0.f, 0.f, 0.f, 0.f};

    const bf16x8* wb = (const bf16x8*)wbS;
    const float* xrow = x + (size_t)(n0 + lo) * CIN;

#pragma unroll
    for (int kb = 0; kb < 7; ++kb) {
        union { bf16x8 b; unsigned short u[8]; } A;
        if (kb < 6 || hi == 0) {
            const float* px = xrow + kb * 32 + hi * 8;
            float4 u0 = *(const float4*)px;
            float4 u1 = *(const float4*)(px + 4);
            A.u[0] = f2bf(u0.x); A.u[1] = f2bf(u0.y);
            A.u[2] = f2bf(u0.z); A.u[3] = f2bf(u0.w);
            A.u[4] = f2bf(u1.x); A.u[5] = f2bf(u1.y);
            A.u[6] = f2bf(u1.z); A.u[7] = f2bf(u1.w);
        } else {
#pragma unroll
            for (int i = 0; i < 8; ++i) A.u[i] = 0;
        }
#pragma unroll
        for (int tt = 0; tt < 4; ++tt)
            acc[tt] = __builtin_amdgcn_mfma_f32_16x16x32_bf16(
                A.b, wb[(kb * 4 + tt) * 64 + lane], acc[tt], 0, 0, 0);
    }

    float ss[4] = {0.f, 0.f, 0.f, 0.f}, ss2[4] = {0.f, 0.f, 0.f, 0.f};
#pragma unroll
    for (int tt = 0; tt < 4; ++tt) {
        const int col = tt * 16 + lo;
#pragma unroll
        for (int r = 0; r < 4; ++r) {
            const int n = n0 + hi * 4 + r;
            float v = acc[tt][r] + bb4[tt];
            t[(size_t)n * 64 + col] = f2bf(v);
            ss[tt] += v;
            ss2[tt] += v * v;
        }
    }

    // stats reduce (same channel held by lanes sharing lane&15)
#pragma unroll
    for (int tt = 0; tt < 4; ++tt) {
        ss[tt]  += __shfl_xor(ss[tt], 16);  ss[tt]  += __shfl_xor(ss[tt], 32);
        ss2[tt] += __shfl_xor(ss2[tt], 16); ss2[tt] += __shfl_xor(ss2[tt], 32);
    }
    __shared__ float ls[4][64], ls2[4][64];
    if (lo == lane) {
#pragma unroll
        for (int tt = 0; tt < 4; ++tt) {
            ls[wloc][tt * 16 + lane]  = ss[tt];
            ls2[wloc][tt * 16 + lane] = ss2[tt];
        }
    }
    __syncthreads();
    if (threadIdx.x < 64) {
        int ch = threadIdx.x;
        atomicAdd(&stats[ch],      ls[0][ch] + ls[1][ch] + ls[2][ch] + ls[3][ch]);
        atomicAdd(&stats[64 + ch], ls2[0][ch] + ls2[1][ch] + ls2[2][ch] + ls2[3][ch]);
    }
}

// fold BN into per-channel affine:  bn(v) = v*a + c
__global__ void finalize_bn(const float* __restrict__ stats,
                            const float* __restrict__ g, const float* __restrict__ b,
                            float* __restrict__ ac)
{
    int c = threadIdx.x;
    float mean = stats[c] * (1.f / NN);
    float var  = stats[64 + c] * (1.f / NN) - mean * mean;
    float rstd = rsqrtf(var + EPSV);
    float a = g[c] * rstd;
    ac[c]      = a;
    ac[64 + c] = b[c] - mean * a;
}

// ---- ln: xnb = bf16(LN(leaky?(affine(u_bf16)))) -------------------------------
template <int RELU>
__global__ __launch_bounds__(256) void ln_kernel(
    const unsigned short* __restrict__ u, const float* __restrict__ ac,
    const float* __restrict__ lng, const float* __restrict__ lnb,
    unsigned short* __restrict__ xnb)
{
    const int lane = threadIdx.x & 63;
    const int wid  = (blockIdx.x * 256 + threadIdx.x) >> 6;
    const int nw   = (gridDim.x * 256) >> 6;
    const float a  = ac[lane],  c0 = ac[64 + lane];
    const float g  = lng[lane], bl = lnb[lane];

    for (int row = wid; row < NN; row += nw) {
        float v = bf2f(u[(size_t)row * 64 + lane]);
        v = v * a + c0;
        if (RELU) v = (v > 0.f) ? v : 0.01f * v;
        float s = v;
#pragma unroll
        for (int off = 32; off > 0; off >>= 1) s += __shfl_xor(s, off);
        float mean = s * (1.f / 64.f);
        float d = v - mean;
        float s2 = d * d;
#pragma unroll
        for (int off = 32; off > 0; off >>= 1) s2 += __shfl_xor(s2, off);
        float rstd = rsqrtf(s2 * (1.f / 64.f) + EPSV);
        float o = d * rstd * g + bl;
        xnb[(size_t)row * 64 + lane] = f2bf(o);
    }
}

// ================= CSR build (graph identical for both layers) ==================
__global__ __launch_bounds__(256) void hist_kernel(
    const int* __restrict__ rowsrc, const int* __restrict__ colsrc,
    int* __restrict__ cnt)
{
    for (int i = blockIdx.x * 256 + threadIdx.x; i < EE; i += gridDim.x * 256) {
        atomicAdd(&cnt[rowsrc[i]], 1);
        atomicAdd(&cnt[NN + colsrc[i]], 1);
    }
}

__global__ __launch_bounds__(256) void scan1_kernel(
    const int* __restrict__ cnt, int* __restrict__ bsum)
{
    const int t = threadIdx.x;
    const int base = blockIdx.x * 1024 + t * 4;
    int s = cnt[base] + cnt[base + 1] + cnt[base + 2] + cnt[base + 3];
    __shared__ int sm[256];
    sm[t] = s;
    __syncthreads();
    for (int off = 1; off < 256; off <<= 1) {
        int v = (t >= off) ? sm[t - off] : 0;
        __syncthreads();
        sm[t] += v;
        __syncthreads();
    }
    if (t == 255) bsum[blockIdx.x] = sm[255];
}

__global__ __launch_bounds__(512) void scan2_kernel(
    const int* __restrict__ bsum, int* __restrict__ bpre, int* __restrict__ ptr)
{
    const int t = threadIdx.x;
    __shared__ int sm[512];
    int orig = bsum[t];
    sm[t] = orig;
    __syncthreads();
    for (int off = 1; off < 512; off <<= 1) {
        int v = (t >= off) ? sm[t - off] : 0;
        __syncthreads();
        sm[t] += v;
        __syncthreads();
    }
    bpre[t] = sm[t] - orig;
    if (t == 0) ptr[NB] = 2 * EE;
}

__global__ __launch_bounds__(256) void scan3_kernel(
    const int* __restrict__ cnt, const int* __restrict__ bpre,
    int* __restrict__ ptr, int* __restrict__ cursor)
{
    const int t = threadIdx.x;
    const int base = blockIdx.x * 1024 + t * 4;
    int c0 = cnt[base], c1 = cnt[base + 1], c2 = cnt[base + 2], c3 = cnt[base + 3];
    int tsum = c0 + c1 + c2 + c3;
    __shared__ int sm[256];
    sm[t] = tsum;
    __syncthreads();
    for (int off = 1; off < 256; off <<= 1) {
        int v = (t >= off) ? sm[t - off] : 0;
        __syncthreads();
        sm[t] += v;
        __syncthreads();
    }
    int p = bpre[blockIdx.x] + sm[t] - tsum;
    ptr[base] = p;     cursor[base] = p;     p += c0;
    ptr[base + 1] = p; cursor[base + 1] = p; p += c1;
    ptr[base + 2] = p; cursor[base + 2] = p; p += c2;
    ptr[base + 3] = p; cursor[base + 3] = p;
}

// ---- windowed fill: 16 windows x 32768 flat-nodes (2.1 MB CSR window each) ----
__global__ __launch_bounds__(256) void fill_win(
    const int* __restrict__ rowsrc, const int* __restrict__ rowdst,
    const float* __restrict__ ratt,
    const int* __restrict__ colsrc, const int* __restrict__ coldst,
    const float* __restrict__ catt,
    int* __restrict__ cursor, int2* __restrict__ edges)
{
    const int x   = blockIdx.x & 7;
    const int sub = blockIdx.x >> 3;
    const int tid = sub * 256 + threadIdx.x;
    const int NT  = (gridDim.x >> 3) * 256;

    {
        const int w = x;
        for (int i = tid; i < EE; i += NT) {
            int s = rowsrc[i];
            if ((s >> 15) == w) {
                int q = atomicAdd(&cursor[s], 1);
                edges[q] = make_int2(rowdst[i], __float_as_int(ratt[i]));
            }
        }
    }
    {
        const int w = x + 8;
        for (int i = tid; i < EE; i += NT) {
            int s = NN + colsrc[i];
            if ((s >> 15) == w) {
                int q = atomicAdd(&cursor[s], 1);
                edges[q] = make_int2(coldst[i], __float_as_int(catt[i]));
            }
        }
    }
}

// ---- pure gather, 4 concurrent streams per wave (R9-proven version) -----------
__global__ __launch_bounds__(256) void gather_kernel(
    const unsigned short* __restrict__ xnb,
    const int* __restrict__ ptr, const int2* __restrict__ edges,
    unsigned short* __restrict__ rxb, unsigned short* __restrict__ cxb,
    float2* __restrict__ attsum)
{
    const int lane = threadIdx.x & 63;
    const int wid  = (blockIdx.x * 256 + threadIdx.x) >> 6;
    const int nw   = (gridDim.x * 256) >> 6;
    const int HALF = NN / 2;

    for (int n = wid; n < HALF; n += nw) {
        const int m = n + HALF;
        const int i0 = ptr[n],      e0 = ptr[n + 1];
        const int i1 = ptr[NN + n], e1 = ptr[NN + n + 1];
        const int i2 = ptr[m],      e2 = ptr[m + 1];
        const int i3 = ptr[NN + m], e3 = ptr[NN + m + 1];
        const int len0 = e0 - i0, len1 = e1 - i1, len2 = e2 - i2, len3 = e3 - i3;
        int maxlen = max(max(len0, len1), max(len2, len3));

        float rx0 = 0.f, cx0 = 0.f, rx1 = 0.f, cx1 = 0.f;
        float ras0 = 0.f, cas0 = 0.f, ras1 = 0.f, cas1 = 0.f;

#pragma unroll 2
        for (int k = 0; k < maxlen; ++k) {
            int j0 = min(i0 + ((k < len0) ? k : 0), 2 * EE - 1);
            int j1 = min(i1 + ((k < len1) ? k : 0), 2 * EE - 1);
            int j2 = min(i2 + ((k < len2) ? k : 0), 2 * EE - 1);
            int j3 = min(i3 + ((k < len3) ? k : 0), 2 * EE - 1);
            int2 p0 = edges[j0];
            int2 p1 = edges[j1];
            int2 p2 = edges[j2];
            int2 p3 = edges[j3];
            float v0 = bf2f(xnb[(size_t)p0.x * 64 + lane]);
            float v1 = bf2f(xnb[(size_t)p1.x * 64 + lane]);
            float v2 = bf2f(xnb[(size_t)p2.x * 64 + lane]);
            float v3 = bf2f(xnb[(size_t)p3.x * 64 + lane]);
            float a0 = (k < len0) ? __int_as_float(p0.y) : 0.f;
            float a1 = (k < len1) ? __int_as_float(p1.y) : 0.f;
            float a2 = (k < len2) ? __int_as_float(p2.y) : 0.f;
            float a3 = (k < len3) ? __int_as_float(p3.y) : 0.f;
            rx0 = fmaf(v0, a0, rx0); ras0 += a0;
            cx0 = fmaf(v1, a1, cx0); cas0 += a1;
            rx1 = fmaf(v2, a2, rx1); ras1 += a2;
            cx1 = fmaf(v3, a3, cx1); cas1 += a3;
        }

        rxb[(size_t)n * 64 + lane] = f2bf(rx0);
        cxb[(size_t)n * 64 + lane] = f2bf(cx0);
        rxb[(size_t)m * 64 + lane] = f2bf(rx1);
        cxb[(size_t)m * 64 + lane] = f2bf(cx1);
        if (lane == 0) {
            attsum[n] = make_float2(ras0, cas0);
            attsum[m] = make_float2(ras1, cas1);
        }
    }
}

// ---- weight pre-swizzle into MFMA B-fragment layout (bf16) --------------------
__global__ __launch_bounds__(256) void w_convert(
    const float* __restrict__ Wrv, const float* __restrict__ Wcv,
    unsigned short* __restrict__ wbuf)
{
    int idx = blockIdx.x * 256 + threadIdx.x;   // 0..16383
    int e    = idx & 7;
    int lane = (idx >> 3) & 63;
    int t    = (idx >> 9) & 3;
    int kb   = (idx >> 11) & 1;
    int m    = (idx >> 12) & 1;
    int L    = (idx >> 13) & 1;
    const float* W = (m ? Wcv : Wrv) + L * 4096;
    float w = W[(kb * 32 + ((lane >> 4) & 3) * 8 + e) * 64 + t * 16 + (lane & 15)];
    wbuf[idx] = f2bf(w);
}

// ---- MFMA epilogue: out = bf16(xnb + rx@Wr + cx@Wc + ras·br + cas·bc) ---------
__global__ __launch_bounds__(256) void gemv_mfma(
    const unsigned short* __restrict__ rxb, const unsigned short* __restrict__ cxb,
    const unsigned short* __restrict__ xnb, const float2* __restrict__ attsum,
    const unsigned short* __restrict__ wb16,
    const float* __restrict__ br, const float* __restrict__ bc,
    unsigned short* __restrict__ out, float* __restrict__ stats)
{
    const int lane = threadIdx.x & 63;
    const int wloc = threadIdx.x >> 6;
    const int wid  = (blockIdx.x * 256 + threadIdx.x) >> 6;
    const int nw   = (gridDim.x * 256) >> 6;
    const int lo   = lane & 15;
    const int hi   = lane >> 4;

    const bf16x8* wb = (const bf16x8*)wb16;
    bf16x8 bfr[2][2][4];
#pragma unroll
    for (int m = 0; m < 2; ++m)
#pragma unroll
        for (int kb = 0; kb < 2; ++kb)
#pragma unroll
            for (int t = 0; t < 4; ++t)
                bfr[m][kb][t] = wb[((m * 2 + kb) * 4 + t) * 64 + lane];

    float brv4[4], bcv4[4];
#pragma unroll
    for (int t = 0; t < 4; ++t) {
        brv4[t] = br[t * 16 + lo];
        bcv4[t] = bc[t * 16 + lo];
    }

    float ss[4] = {0.f, 0.f, 0.f, 0.f}, ss2[4] = {0.f, 0.f, 0.f, 0.f};
    const bf16x8* ra = (const bf16x8*)rxb;
    const bf16x8* ca = (const bf16x8*)cxb;

    for (int tile = wid; tile < NN / 16; tile += nw) {
        const int n0 = tile * 16;
        const int arow = n0 + lo;
        bf16x8 a0 = ra[arow * 8 + hi];
        bf16x8 a1 = ra[arow * 8 + 4 + hi];
        bf16x8 c0 = ca[arow * 8 + hi];
        bf16x8 c1 = ca[arow * 8 + 4 + hi];
        float2 an[4];
#pragma unroll
        for (int r = 0; r < 4; ++r) an[r] = attsum[n0 + hi * 4 + r];

#pragma unroll
        for (int t = 0; t < 4; ++t) {
            f32x4 acc = {0.f, 0.f, 0.f, 0.f};
            acc = __builtin_amdgcn_mfma_f32_16x16x32_bf16(a0, bfr[0][0][t], acc, 0, 0, 0);
            acc = __builtin_amdgcn_mfma_f32_16x16x32_bf16(a1, bfr[0][1][t], acc, 0, 0, 0);
            acc = __builtin_amdgcn_mfma_f32_16x16x32_bf16(c0, bfr[1][0][t], acc, 0, 0, 0);
            acc = __builtin_amdgcn_mfma_f32_16x16x32_bf16(c1, bfr[1][1][t], acc, 0, 0, 0);
            const int col = t * 16 + lo;
#pragma unroll
            for (int r = 0; r < 4; ++r) {
                const int n = n0 + hi * 4 + r;
                float v = acc[r] + bf2f(xnb[(size_t)n * 64 + col])
                        + an[r].x * brv4[t] + an[r].y * bcv4[t];
                out[(size_t)n * 64 + col] = f2bf(v);
                ss[t] += v;
                ss2[t] += v * v;
            }
        }
    }

    // stats reduce: lanes sharing the same (lane&15) hold the same channels
#pragma unroll
    for (int t = 0; t < 4; ++t) {
        ss[t]  += __shfl_xor(ss[t], 16);  ss[t]  += __shfl_xor(ss[t], 32);
        ss2[t] += __shfl_xor(ss2[t], 16); ss2[t] += __shfl_xor(ss2[t], 32);
    }
    __shared__ float ls[4][64], ls2[4][64];
    if (lo == lane) {   // lanes 0..15
#pragma unroll
        for (int t = 0; t < 4; ++t) {
            ls[wloc][t * 16 + lane]  = ss[t];
            ls2[wloc][t * 16 + lane] = ss2[t];
        }
    }
    __syncthreads();
    if (threadIdx.x < 64) {
        int ch = threadIdx.x;
        atomicAdd(&stats[ch],      ls[0][ch] + ls[1][ch] + ls[2][ch] + ls[3][ch]);
        atomicAdd(&stats[64 + ch], ls2[0][ch] + ls2[1][ch] + ls2[2][ch] + ls2[3][ch]);
    }
}

// ------ fused output: affine+leaky -> logits = h@smW + b -> softmax ------------
__global__ __launch_bounds__(256) void out_kernel(
    const unsigned short* __restrict__ agg, const float* __restrict__ ac,
    const float* __restrict__ smW, const float* __restrict__ smb,
    float* __restrict__ out)
{
    __shared__ float sW[64 * 16];
    for (int i = threadIdx.x; i < 64 * 16; i += 256) sW[i] = smW[i];
    __syncthreads();
    const int j = threadIdx.x & 15;
    const int rloc = threadIdx.x >> 4;
    const float bj = smb[j];
    for (int row = blockIdx.x * 16 + rloc; row < NN; row += gridDim.x * 16) {
        float acc = bj;
#pragma unroll
        for (int k = 0; k < 64; ++k) {
            float v = bf2f(agg[(size_t)row * 64 + k]);
            v = v * ac[k] + ac[64 + k];
            v = (v > 0.f) ? v : 0.01f * v;
            acc = fmaf(v, sW[k * 16 + j], acc);
        }
        float m = acc;
#pragma unroll
        for (int off = 8; off > 0; off >>= 1) m = fmaxf(m, __shfl_xor(m, off));
        float e = expf(acc - m);
        float ssum = e;
#pragma unroll
        for (int off = 8; off > 0; off >>= 1) ssum += __shfl_xor(ssum, off);
        out[(size_t)row * 16 + j] = e / ssum;
    }
}

// ------------------------------------------------------------------------------
extern "C" void kernel_launch(void* const* d_in, const int* in_sizes, int n_in,
                              void* d_out, int out_size, void* d_ws, size_t ws_size,
                              hipStream_t stream)
{
    const float* x        = (const float*)d_in[0];
    const float* row_att  = (const float*)d_in[1];
    const float* col_att  = (const float*)d_in[2];
    const float* prelin_W = (const float*)d_in[3];
    const float* prelin_b = (const float*)d_in[4];
    const float* bn0_g    = (const float*)d_in[5];
    const float* bn0_b    = (const float*)d_in[6];
    const float* ln_g     = (const float*)d_in[7];
    const float* ln_b     = (const float*)d_in[8];
    const float* Wrv      = (const float*)d_in[9];
    const float* brv      = (const float*)d_in[10];
    const float* Wcv      = (const float*)d_in[11];
    const float* bcv      = (const float*)d_in[12];
    const float* bn_g     = (const float*)d_in[13];
    const float* bn_b     = (const float*)d_in[14];
    const float* sm_W     = (const float*)d_in[15];
    const float* sm_b     = (const float*)d_in[16];
    const int*   rowsrc   = (const int*)d_in[17];
    const int*   rowdst   = (const int*)d_in[18];
    const int*   colsrc   = (const int*)d_in[19];
    const int*   coldst   = (const int*)d_in[20];
    float* out = (float*)d_out;

    // ---- workspace layout (~150 MB) ----
    const size_t NH = (size_t)NN * 64;
    char* extra = (char*)d_ws;
    unsigned short* A   = (unsigned short*)extra; extra += NH * sizeof(short);  // layer act (bf16)
    unsigned short* xnb = (unsigned short*)extra; extra += NH * sizeof(short);
    unsigned short* rxb = (unsigned short*)extra; extra += NH * sizeof(short);
    unsigned short* cxb = (unsigned short*)extra; extra += NH * sizeof(short);
    float2* attsum = (float2*)extra;              extra += (size_t)NN * sizeof(float2);
    float* stats  = (float*)extra;                extra += 3 * 128 * sizeof(float);
    float* ac     = (float*)extra;                extra += 3 * 128 * sizeof(float);
    unsigned short* wbuf  = (unsigned short*)extra; extra += 16384 * sizeof(short);
    unsigned short* wbufS = (unsigned short*)extra; extra += 14336 * sizeof(short);
    int*   bsum   = (int*)extra;                  extra += 512 * sizeof(int);
    int*   bpre   = (int*)extra;                  extra += 512 * sizeof(int);
    int*   ptr    = (int*)extra;                  extra += (NB + 1) * sizeof(int);
    int*   counts = (int*)extra;                  extra += NB * sizeof(int);
    int*   cursor = (int*)extra;                  extra += NB * sizeof(int);
    int2*  edges  = (int2*)extra;                 extra += 2 * (size_t)EE * sizeof(int2);

    hipMemsetAsync(stats, 0, 3 * 128 * sizeof(float), stream);
    hipMemsetAsync(counts, 0, NB * sizeof(int), stream);

    // ---- CSR build (used by both layers) ----
    hist_kernel<<<2048, 256, 0, stream>>>(rowsrc, colsrc, counts);
    scan1_kernel<<<512, 256, 0, stream>>>(counts, bsum);
    scan2_kernel<<<1, 512, 0, stream>>>(bsum, bpre, ptr);
    scan3_kernel<<<512, 256, 0, stream>>>(counts, bpre, ptr, cursor);
    fill_win<<<2048, 256, 0, stream>>>(rowsrc, rowdst, row_att,
                                       colsrc, coldst, col_att,
                                       cursor, edges);
    w_convert<<<64, 256, 0, stream>>>(Wrv, Wcv, wbuf);
    w_convert_stem<<<56, 256, 0, stream>>>(prelin_W, wbufS);

    // ---- stem (MFMA, stats fused) ----
    stem_mfma<<<NN / 64, 256, 0, stream>>>(x, wbufS, prelin_b, A, stats);
    finalize_bn<<<1, 64, 0, stream>>>(stats, bn0_g, bn0_b, ac);

    // ---- layer 0 ----
    ln_kernel<0><<<4096, 256, 0, stream>>>(A, ac, ln_g, ln_b, xnb);
    gather_kernel<<<8192, 256, 0, stream>>>(xnb, ptr, edges, rxb, cxb, attsum);
    gemv_mfma<<<2048, 256, 0, stream>>>(rxb, cxb, xnb, attsum, wbuf,
                                        brv, bcv, A, stats + 128);
    finalize_bn<<<1, 64, 0, stream>>>(stats + 128, bn_g, bn_b, ac + 128);

    // ---- layer 1 ----
    ln_kernel<1><<<4096, 256, 0, stream>>>(A, ac + 128, ln_g + 64, ln_b + 64, xnb);
    gather_kernel<<<8192, 256, 0, stream>>>(xnb, ptr, edges, rxb, cxb, attsum);
    gemv_mfma<<<2048, 256, 0, stream>>>(rxb, cxb, xnb, attsum, wbuf + 8192,
                                        brv + 64, bcv + 64, A, stats + 256);
    finalize_bn<<<1, 64, 0, stream>>>(stats + 256, bn_g + 64, bn_b + 64, ac + 256);

    // ---- output head ----
    out_kernel<<<2048, 256, 0, stream>>>(A, ac + 256, sm_W, sm_b, out);
}